// Round 12
// baseline (98.556 us; speedup 1.0000x reference)
//
#include <hip/hip_runtime.h>

// Depthwise 7x7 VALID conv, fp32, NCHW.
// x: (16,256,128,128), w: (256,7,7), out: (16,256,122,122)
// Column-sweep with 7-slot ring accumulator (R9/R10) + 1-step lookahead
// ping-pong window (f0/f1, fully static parity): next row's 4 float2 loads
// issue BEFORE current row's 98 FMAs, so each step's load latency hides
// under the previous step's arithmetic (waitcnt vmcnt(4), not vmcnt(0)).
// Block = one image, 4 waves = 4 row-quarters (r0 in {0,30,60,90}, 38-row
// sweep -> 32 output rows each; overlaps written with identical values).
// lanes 0-31: cols 0..63; lanes 32-63: cols 58..121 (overlap identical).
// No LDS, no bounds checks, no launch-bounds min-waves hint (demotion!).

#define BATCH 16
#define CHAN  256
#define H_IN  128
#define W_IN  128
#define KS    7
#define H_OUT 122
#define W_OUT 122

typedef float v2f __attribute__((ext_vector_type(2)));

__device__ __forceinline__ float sgpr_bcast(float v) {
    return __int_as_float(__builtin_amdgcn_readfirstlane(__float_as_int(v)));
}

__global__ __launch_bounds__(256)
void dwconv7x7_kernel(const float* __restrict__ x,
                      const float* __restrict__ w,
                      float* __restrict__ out) {
    const int lane = threadIdx.x & 63;
    const int img  = blockIdx.x;                 // b*CHAN + c (one image/block)
    const int q    = threadIdx.x >> 6;           // row-quarter 0..3
    const int ch   = img & (CHAN - 1);

    int c = 2 * lane;                 // lanes 0..31 -> cols 0..62
    if (lane >= 32) c -= 6;           // lanes 32..63 -> cols 58..120
    const int r0 = 30 * q;            // 0,30,60,90; sweep rows r0..r0+37

    // ---- weights: block-uniform -> force into SGPRs ----
    const float* __restrict__ wp = w + ch * (KS * KS);
    float wr[KS * KS];
    #pragma unroll
    for (int i = 0; i < KS * KS; ++i) wr[i] = sgpr_bcast(wp[i]);

    // input cols c..c+7 (max 127), rows r0..r0+37 (max 127): all in bounds
    const float* __restrict__ xq =
        x + (size_t)img * (H_IN * W_IN) + (size_t)r0 * W_IN + c;
    float* __restrict__ oq =
        out + (size_t)img * (H_OUT * W_OUT) + (size_t)r0 * W_OUT + c;

    float acc[KS][2] = {};            // ring: slot = (local output row) % 7
    float f0[8], f1[8];               // ping-pong window buffers

    #define LOADW(B) do {                                                  \
        const v2f a0 = *reinterpret_cast<const v2f*>(xq);                  \
        const v2f a1 = *reinterpret_cast<const v2f*>(xq + 2);              \
        const v2f a2 = *reinterpret_cast<const v2f*>(xq + 4);              \
        const v2f a3 = *reinterpret_cast<const v2f*>(xq + 6);              \
        B[0] = a0.x; B[1] = a0.y; B[2] = a1.x; B[3] = a1.y;                \
        B[4] = a2.x; B[5] = a2.y; B[6] = a3.x; B[7] = a3.y; } while (0)

    #define ACCUMF(F, SLOT, KY) do {                                       \
        _Pragma("unroll")                                                  \
        for (int kx = 0; kx < 7; ++kx) {                                   \
            const float wv = wr[(KY) * 7 + kx];                            \
            acc[(SLOT)][0] = fmaf(F[kx],     wv, acc[(SLOT)][0]);          \
            acc[(SLOT)][1] = fmaf(F[kx + 1], wv, acc[(SLOT)][1]);          \
        } } while (0)

    // main step: issue next row's loads into FN, then compute row from FC
    #define MSTEP(U, FC, FN) do {                                          \
        xq += W_IN;                                                        \
        LOADW(FN);                                                         \
        _Pragma("unroll")                                                  \
        for (int ky = 0; ky < KS; ++ky)                                    \
            ACCUMF(FC, (6 + (U) - ky + 7) % KS, ky);                       \
        v2f v; v.x = acc[(U)][0]; v.y = acc[(U)][1];                       \
        __builtin_nontemporal_store(v, reinterpret_cast<v2f*>(oq));        \
        acc[(U)][0] = 0.f; acc[(U)][1] = 0.f;                              \
        oq += W_OUT; } while (0)

    #define MSTEP_LAST(U, FC) do {                                         \
        _Pragma("unroll")                                                  \
        for (int ky = 0; ky < KS; ++ky)                                    \
            ACCUMF(FC, (6 + (U) - ky + 7) % KS, ky);                       \
        v2f v; v.x = acc[(U)][0]; v.y = acc[(U)][1];                       \
        __builtin_nontemporal_store(v, reinterpret_cast<v2f*>(oq));        \
        } while (0)

    // ---- prologue: row 0 pre-load; steps s=0..5 (partial ky), ping-pong ----
    LOADW(f0);                                   // row 0
    xq += W_IN; LOADW(f1);                       // s=0: load row 1
    ACCUMF(f0, 0, 0);
    xq += W_IN; LOADW(f0);                       // s=1: load row 2
    ACCUMF(f1, 1, 0); ACCUMF(f1, 0, 1);
    xq += W_IN; LOADW(f1);                       // s=2: load row 3
    ACCUMF(f0, 2, 0); ACCUMF(f0, 1, 1); ACCUMF(f0, 0, 2);
    xq += W_IN; LOADW(f0);                       // s=3: load row 4
    ACCUMF(f1, 3, 0); ACCUMF(f1, 2, 1); ACCUMF(f1, 1, 2); ACCUMF(f1, 0, 3);
    xq += W_IN; LOADW(f1);                       // s=4: load row 5
    ACCUMF(f0, 4, 0); ACCUMF(f0, 3, 1); ACCUMF(f0, 2, 2); ACCUMF(f0, 1, 3);
    ACCUMF(f0, 0, 4);
    xq += W_IN; LOADW(f0);                       // s=5: load row 6
    ACCUMF(f1, 5, 0); ACCUMF(f1, 4, 1); ACCUMF(f1, 3, 2); ACCUMF(f1, 2, 3);
    ACCUMF(f1, 1, 4); ACCUMF(f1, 0, 5);

    // ---- main: 28 steps (s=6..33) as 2 x 14 (even unroll -> static parity)
    for (int sb = 0; sb < 2; ++sb) {
        MSTEP(0, f0, f1); MSTEP(1, f1, f0); MSTEP(2, f0, f1);
        MSTEP(3, f1, f0); MSTEP(4, f0, f1); MSTEP(5, f1, f0);
        MSTEP(6, f0, f1);
        MSTEP(0, f1, f0); MSTEP(1, f0, f1); MSTEP(2, f1, f0);
        MSTEP(3, f0, f1); MSTEP(4, f1, f0); MSTEP(5, f0, f1);
        MSTEP(6, f1, f0);
    }

    // ---- tail: s=34..37 (u=0..3, parity 0,1,0,1); s=37 consumes row 37 ----
    MSTEP(0, f0, f1); MSTEP(1, f1, f0); MSTEP(2, f0, f1);   // loads row 37
    MSTEP_LAST(3, f1);

    #undef LOADW
    #undef ACCUMF
    #undef MSTEP
    #undef MSTEP_LAST
}

extern "C" void kernel_launch(void* const* d_in, const int* in_sizes, int n_in,
                              void* d_out, int out_size, void* d_ws, size_t ws_size,
                              hipStream_t stream) {
    const float* x = (const float*)d_in[0];
    const float* w = (const float*)d_in[1];
    float* out = (float*)d_out;

    // one block per image; 4 waves = 4 row-quarters
    dim3 grid(BATCH * CHAN, 1, 1);   // 4096 blocks
    dim3 block(256, 1, 1);
    dwconv7x7_kernel<<<grid, block, 0, stream>>>(x, w, out);
}

// Round 13
// 97.080 us; speedup vs baseline: 1.0152x; 1.0152x over previous
//
#include <hip/hip_runtime.h>

// Depthwise 7x7 VALID conv, fp32, NCHW.
// x: (16,256,128,128), w: (256,7,7), out: (16,256,122,122)
// R10 column-sweep (7-slot ring accumulator, block = one image, 4 waves =
// 4 row-quarters r0 in {0,30,60,90}, 38-row sweep -> 32 output rows) with
// PACKED fp32 math: each lane's column pair (c, c+1) lives in a v2f, inner
// loop is 49 v_pk_fma_f32 per row-step (vs 98 scalar v_fma_f32).
// Window: 4 aligned v2f loads + 3 shifted pairs assembled once per row.
// No LDS, no bounds checks, no launch-bounds min-waves hint (demotion!),
// no software pipelining (R11: +12 VGPR crossed the 64 cliff).
// lanes 0-31: cols 0..63; lanes 32-63: cols 58..121 (overlap identical).

#define BATCH 16
#define CHAN  256
#define H_IN  128
#define W_IN  128
#define KS    7
#define H_OUT 122
#define W_OUT 122

typedef float v2f __attribute__((ext_vector_type(2)));

__device__ __forceinline__ float sgpr_bcast(float v) {
    return __int_as_float(__builtin_amdgcn_readfirstlane(__float_as_int(v)));
}

__global__ __launch_bounds__(256)
void dwconv7x7_kernel(const float* __restrict__ x,
                      const float* __restrict__ w,
                      float* __restrict__ out) {
    const int lane = threadIdx.x & 63;
    const int img  = blockIdx.x;                 // b*CHAN + c (one image/block)
    const int q    = threadIdx.x >> 6;           // row-quarter 0..3
    const int ch   = img & (CHAN - 1);

    int c = 2 * lane;                 // lanes 0..31 -> cols 0..62
    if (lane >= 32) c -= 6;           // lanes 32..63 -> cols 58..120
    const int r0 = 30 * q;            // 0,30,60,90; sweep rows r0..r0+37

    // ---- weights: block-uniform -> force into SGPRs ----
    const float* __restrict__ wp = w + ch * (KS * KS);
    float wr[KS * KS];
    #pragma unroll
    for (int i = 0; i < KS * KS; ++i) wr[i] = sgpr_bcast(wp[i]);

    // input cols c..c+7 (max 127), rows r0..r0+37 (max 127): all in bounds
    const float* __restrict__ xq =
        x + (size_t)img * (H_IN * W_IN) + (size_t)r0 * W_IN + c;
    float* __restrict__ oq =
        out + (size_t)img * (H_OUT * W_OUT) + (size_t)r0 * W_OUT + c;

    v2f acc[KS];                      // ring: slot = (local output row) % 7
    #pragma unroll
    for (int i = 0; i < KS; ++i) { acc[i].x = 0.f; acc[i].y = 0.f; }

    v2f p[4];                         // aligned window pairs (f0f1..f6f7)
    v2f sh[3];                        // shifted pairs (f1f2, f3f4, f5f6)

    #define LOADW() do {                                                   \
        p[0] = *reinterpret_cast<const v2f*>(xq);                          \
        p[1] = *reinterpret_cast<const v2f*>(xq + 2);                      \
        p[2] = *reinterpret_cast<const v2f*>(xq + 4);                      \
        p[3] = *reinterpret_cast<const v2f*>(xq + 6);                      \
        sh[0].x = p[0].y; sh[0].y = p[1].x;                                \
        sh[1].x = p[1].y; sh[1].y = p[2].x;                                \
        sh[2].x = p[2].y; sh[2].y = p[3].x; } while (0)

    #define ACCUM(SLOT, KY) do {                                           \
        _Pragma("unroll")                                                  \
        for (int kx = 0; kx < 7; ++kx) {                                   \
            const float wv = wr[(KY) * 7 + kx];                            \
            v2f wpair; wpair.x = wv; wpair.y = wv;                         \
            const v2f src = (kx & 1) ? sh[kx >> 1] : p[kx >> 1];           \
            acc[(SLOT)] = __builtin_elementwise_fma(src, wpair, acc[(SLOT)]); \
        } } while (0)

    #define MAINSTEP(U) do {                                               \
        LOADW();                                                           \
        _Pragma("unroll")                                                  \
        for (int ky = 0; ky < KS; ++ky)                                    \
            ACCUM((6 + (U) - ky + 7) % KS, ky);                            \
        __builtin_nontemporal_store(acc[(U)], reinterpret_cast<v2f*>(oq)); \
        acc[(U)].x = 0.f; acc[(U)].y = 0.f;                                \
        xq += W_IN; oq += W_OUT; } while (0)

    // ---- prologue: s = 0..5, only ky <= s ----
    #pragma unroll
    for (int s = 0; s < 6; ++s) {
        LOADW();
        #pragma unroll
        for (int ky = 0; ky <= s; ++ky)
            ACCUM((s - ky) % KS, ky);
        xq += W_IN;
    }

    // ---- main: 28 steps (s=6..33), slot/store index u = (s-6) % 7 ----
    for (int sb = 0; sb < 4; ++sb) {
        #pragma unroll
        for (int u = 0; u < 7; ++u) {
            MAINSTEP(u);
        }
    }

    // ---- tail: 4 steps (s=34..37, u=0..3) ----
    #pragma unroll
    for (int t = 0; t < 4; ++t) {
        MAINSTEP(t);
    }

    #undef LOADW
    #undef ACCUM
    #undef MAINSTEP
}

extern "C" void kernel_launch(void* const* d_in, const int* in_sizes, int n_in,
                              void* d_out, int out_size, void* d_ws, size_t ws_size,
                              hipStream_t stream) {
    const float* x = (const float*)d_in[0];
    const float* w = (const float*)d_in[1];
    float* out = (float*)d_out;

    // one block per image; 4 waves = 4 row-quarters
    dim3 grid(BATCH * CHAN, 1, 1);   // 4096 blocks
    dim3 block(256, 1, 1);
    dwconv7x7_kernel<<<grid, block, 0, stream>>>(x, w, out);
}

// Round 14
// 94.229 us; speedup vs baseline: 1.0459x; 1.0303x over previous
//
#include <hip/hip_runtime.h>
#include <stdint.h>

// Depthwise 7x7 VALID conv, fp32, NCHW.
// x: (16,256,128,128), w: (256,7,7), out: (16,256,122,122)
// DMA-pipelined column sweep:
//  - block = one image, 4 waves = 4 row-quarters (r0 = 30q, 38-row sweep,
//    32 output rows; q>0 skips its first 2 duplicate row stores).
//  - lanes 0-31: col pair c=2*lane; lanes 32-63: c=2*lane-6 (dup cols benign).
//  - wave-private LDS ring: 4 slots x 2 rows x 128 floats (1 KB/slot).
//    Each macro-step: 1 global_load_lds (64 lanes x 16B = 2 rows) staged
//    3 pairs ahead, counted s_waitcnt vmcnt(N) (never 0), then 2 rows of
//    4x ds_read_b64 window + 49 packed FMA + 1 store each.
//  - 8-slot accumulator ring (v2f acc[8]) -> ALL indices compile-time.
//  - empty asm memory fences pin VMEM issue order so vmcnt counts are exact.
//  - no launch_bounds min-waves hint (R2/R5/R7: triggers scratch demotion).

#define BATCH 16
#define CHAN  256
#define H_IN  128
#define W_IN  128
#define KS    7
#define H_OUT 122
#define W_OUT 122

typedef float v2f __attribute__((ext_vector_type(2)));

__device__ __forceinline__ float sgpr_bcast(float v) {
    return __int_as_float(__builtin_amdgcn_readfirstlane(__float_as_int(v)));
}

__global__ __launch_bounds__(256)
void dwconv7x7_kernel(const float* __restrict__ x,
                      const float* __restrict__ w,
                      float* __restrict__ out) {
    __shared__ float lds[4][4][256];   // [wave][slot][2 rows x 128 floats]

    const int lane = threadIdx.x & 63;
    const int q    = threadIdx.x >> 6;           // row-quarter 0..3
    const int img  = blockIdx.x;                 // b*CHAN + c
    const int ch   = img & (CHAN - 1);

    int c = 2 * lane;                 // lanes 0..31 -> cols 0..62
    if (lane >= 32) c -= 6;           // lanes 32..63 -> cols 58..120
    const int r0 = 30 * q;            // sweep input rows r0..r0+37

    // ---- weights: block-uniform -> force into SGPRs ----
    const float* __restrict__ wp = w + ch * (KS * KS);
    float wr[KS * KS];
    #pragma unroll
    for (int i = 0; i < KS * KS; ++i) wr[i] = sgpr_bcast(wp[i]);

    // per-lane global source pointer for DMA staging (16B per lane = 4 floats;
    // 64 lanes cover exactly 2 rows of 128 floats, contiguous in memory)
    const float* xstage =
        x + (size_t)img * (H_IN * W_IN) + (size_t)r0 * W_IN + lane * 4;
    float* oq =
        out + (size_t)img * (H_OUT * W_OUT) + (size_t)r0 * W_OUT + c;

    v2f acc[8];                       // ring: slot = (local output row) % 8
    #pragma unroll
    for (int i = 0; i < 8; ++i) { acc[i].x = 0.f; acc[i].y = 0.f; }

    // fence first so stage order is pinned (vmcnt counts depend on it)
    #define STAGE(SLOT) do {                                               \
        asm volatile("" ::: "memory");                                     \
        __builtin_amdgcn_global_load_lds(                                  \
            (const __attribute__((address_space(1))) void*)xstage,         \
            (__attribute__((address_space(3))) void*)&lds[q][SLOT][0],     \
            16, 0, 0);                                                     \
        xstage += 2 * W_IN; } while (0)

    #define WAITV(N) asm volatile("s_waitcnt vmcnt(" #N ")" ::: "memory")

    // one input row: 4x ds_read_b64 window + packed FMA into acc ring
    #define ROWD(SM8, LSLOT, HALF, KYLO, KYHI) do {                        \
        const float* rl = &lds[q][LSLOT][(HALF) * 128];                    \
        const v2f p0 = *(const v2f*)(rl + c);                              \
        const v2f p1 = *(const v2f*)(rl + c + 2);                          \
        const v2f p2 = *(const v2f*)(rl + c + 4);                          \
        const v2f p3 = *(const v2f*)(rl + c + 6);                          \
        v2f s0, s1, s2;                                                    \
        s0.x = p0.y; s0.y = p1.x;                                          \
        s1.x = p1.y; s1.y = p2.x;                                          \
        s2.x = p2.y; s2.y = p3.x;                                          \
        const v2f srcv[7] = {p0, s0, p1, s1, p2, s2, p3};                  \
        _Pragma("unroll")                                                  \
        for (int ky = (KYLO); ky <= (KYHI); ++ky) {                        \
            _Pragma("unroll")                                              \
            for (int kx = 0; kx < 7; ++kx) {                               \
                const float wv = wr[ky * 7 + kx];                          \
                v2f wpair; wpair.x = wv; wpair.y = wv;                     \
                acc[((SM8) - ky + 8) & 7] = __builtin_elementwise_fma(     \
                    srcv[kx], wpair, acc[((SM8) - ky + 8) & 7]);           \
            }                                                              \
        } } while (0)

    #define ST(OSLOT) do {                                                 \
        __builtin_nontemporal_store(acc[OSLOT], (v2f*)oq);                 \
        acc[OSLOT].x = 0.f; acc[OSLOT].y = 0.f;                           \
        oq += W_OUT; } while (0)

    #define STSKIP(OSLOT) do {                                             \
        if (q == 0) __builtin_nontemporal_store(acc[OSLOT], (v2f*)oq);     \
        acc[OSLOT].x = 0.f; acc[OSLOT].y = 0.f;                           \
        oq += W_OUT; } while (0)

    // ---- prologue staging: pairs 0,1,2 -> slots 0,1,2 ----
    STAGE(0); STAGE(1); STAGE(2);

    // m=0: rows 0,1 (partial ky)
    STAGE(3); WAITV(3);
    ROWD(0, 0, 0, 0, 0);
    ROWD(1, 0, 1, 0, 1);
    // m=1: rows 2,3
    STAGE(0); WAITV(3);
    ROWD(2, 1, 0, 0, 2);
    ROWD(3, 1, 1, 0, 3);
    // m=2: rows 4,5
    STAGE(1); WAITV(3);
    ROWD(4, 2, 0, 0, 4);
    ROWD(5, 2, 1, 0, 5);
    // m=3: rows 6,7; first stores o=0,1 (dup rows for q>0 -> skip)
    STAGE(2); WAITV(3);
    ROWD(6, 3, 0, 0, 6); STSKIP(0);
    ROWD(7, 3, 1, 0, 6); STSKIP(1);
    // m=4: rows 8,9
    STAGE(3); WAITV(3);
    ROWD(0, 0, 0, 0, 6); ST(2);
    ROWD(1, 0, 1, 0, 6); ST(3);
    // m=5: rows 10,11
    STAGE(0); WAITV(5);
    ROWD(2, 1, 0, 0, 6); ST(4);
    ROWD(3, 1, 1, 0, 6); ST(5);
    // m=6: rows 12,13
    STAGE(1); WAITV(7);
    ROWD(4, 2, 0, 0, 6); ST(6);
    ROWD(5, 2, 1, 0, 6); ST(7);

    // ---- steady: m=7..14 (2 reps x 4 macro-steps), vmcnt(9) counted ----
    for (int rep = 0; rep < 2; ++rep) {
        STAGE(2); WAITV(9);
        ROWD(6, 3, 0, 0, 6); ST(0);
        ROWD(7, 3, 1, 0, 6); ST(1);
        STAGE(3); WAITV(9);
        ROWD(0, 0, 0, 0, 6); ST(2);
        ROWD(1, 0, 1, 0, 6); ST(3);
        STAGE(0); WAITV(9);
        ROWD(2, 1, 0, 0, 6); ST(4);
        ROWD(3, 1, 1, 0, 6); ST(5);
        STAGE(1); WAITV(9);
        ROWD(4, 2, 0, 0, 6); ST(6);
        ROWD(5, 2, 1, 0, 6); ST(7);
    }

    // ---- tail: m=15..18 (last stage at m=15; decreasing counted waits) ----
    STAGE(2); WAITV(9);
    ROWD(6, 3, 0, 0, 6); ST(0);
    ROWD(7, 3, 1, 0, 6); ST(1);
    WAITV(8);
    ROWD(0, 0, 0, 1, 6); ST(2);
    ROWD(1, 0, 1, 2, 6); ST(3);
    WAITV(7);
    ROWD(2, 1, 0, 3, 6); ST(4);
    ROWD(3, 1, 1, 4, 6); ST(5);
    WAITV(6);
    ROWD(4, 2, 0, 5, 6); ST(6);
    ROWD(5, 2, 1, 6, 6); ST(7);

    #undef STAGE
    #undef WAITV
    #undef ROWD
    #undef ST
    #undef STSKIP
}

extern "C" void kernel_launch(void* const* d_in, const int* in_sizes, int n_in,
                              void* d_out, int out_size, void* d_ws, size_t ws_size,
                              hipStream_t stream) {
    const float* x = (const float*)d_in[0];
    const float* w = (const float*)d_in[1];
    float* out = (float*)d_out;

    // one block per image; 4 waves = 4 row-quarters
    dim3 grid(BATCH * CHAN, 1, 1);   // 4096 blocks
    dim3 block(256, 1, 1);
    dwconv7x7_kernel<<<grid, block, 0, stream>>>(x, w, out);
}